// Round 1
// baseline (1902.873 us; speedup 1.0000x reference)
//
#include <hip/hip_runtime.h>
#include <hip/hip_bf16.h>

#define N_NODES 16384
#define N_EDGES 65536
#define NB      32
#define H       64
#define NLAYERS 3
#define NEG     0.1f
#define LN_EPS  1e-5f

__device__ __forceinline__ float leaky(float v) { return v > 0.f ? v : NEG * v; }

// ---------------------------------------------------------------- degree
__global__ __launch_bounds__(256) void k_deg(const int* __restrict__ dst,
                                             float* __restrict__ deg) {
    int e = blockIdx.x * 256 + threadIdx.x;
    if (e < N_EDGES) atomicAdd(&deg[dst[e]], 1.0f);
}

// ---------------------------------------------------------------- input proj
__global__ __launch_bounds__(256) void k_inproj(const float* __restrict__ x,
                                                const float* __restrict__ Win,
                                                const float* __restrict__ bin,
                                                float* __restrict__ h) {
    int t = blockIdx.x * 256 + threadIdx.x;   // over N*H
    int n = t >> 6, j = t & 63;
    const float* xr = x + n * 4;
    const float* wr = Win + j * 4;
    float v = bin[j] + xr[0] * wr[0] + xr[1] * wr[1] + xr[2] * wr[2] + xr[3] * wr[3];
    h[t] = leaky(v);
}

// ---------------------------------------------------------------- Bm = transpose(ew3) (+bias rows)
// Bm[(i*64+k)*64 + o] = ew3[(i*64+o)*64 + k];  Bm[262144 + i*64+o] = eb3[i*64+o]
__global__ __launch_bounds__(256) void k_prep_bm(const float* __restrict__ ew3l,
                                                 const float* __restrict__ eb3l,
                                                 float* __restrict__ Bm) {
    __shared__ float tile[64][65];
    int i = blockIdx.x;            // 0..63
    int t = threadIdx.x;
    for (int idx = t; idx < 4096; idx += 256) {
        int o = idx >> 6, k = idx & 63;
        tile[o][k] = ew3l[((i << 6) + o) * 64 + k];   // coalesced read
    }
    __syncthreads();
    for (int idx = t; idx < 4096; idx += 256) {
        int k = idx >> 6, o = idx & 63;
        Bm[((i << 6) + k) * 64 + o] = tile[o][k];     // coalesced write
    }
    if (i == 0) {
        for (int idx = t; idx < 4096; idx += 256) Bm[262144 + idx] = eb3l[idx];
    }
}

// ---------------------------------------------------------------- edge MLP stages 1+2
__global__ __launch_bounds__(256) void k_edge_mlp(const float* __restrict__ ea,
                                                  const float* __restrict__ w1,
                                                  const float* __restrict__ b1,
                                                  const float* __restrict__ w2,
                                                  const float* __restrict__ b2,
                                                  float* __restrict__ e2out) {
    __shared__ float w2s[64][65];
    __shared__ float e1s[4][64];
    int t = threadIdx.x;
    for (int idx = t; idx < 4096; idx += 256) w2s[idx >> 6][idx & 63] = w2[idx];
    int el = t >> 6, j = t & 63;
    int e = blockIdx.x * 4 + el;
    const float* ar  = ea + e * 5;
    const float* w1r = w1 + j * 5;
    float v = b1[j];
#pragma unroll
    for (int d = 0; d < 5; d++) v += ar[d] * w1r[d];
    e1s[el][j] = leaky(v);
    __syncthreads();
    float v2 = b2[j];
#pragma unroll 8
    for (int k = 0; k < 64; k++) v2 += e1s[el][k] * w2s[j][k];
    e2out[e * 64 + j] = leaky(v2);
}

// ---------------------------------------------------------------- fused bilinear GEMM + scatter
// msg[e,o] = sum_{i,k} h[src,i]*e2[e,k]*Bm[(i*64+k)*64+o] + sum_i h[src,i]*Bm[(4096+i)*64+o]
__global__ __launch_bounds__(256, 4) void k_msg(const float* __restrict__ h,
                                                const float* __restrict__ e2,
                                                const float* __restrict__ Bm,
                                                const int* __restrict__ src,
                                                const int* __restrict__ dst,
                                                float* __restrict__ agg) {
    __shared__ float hsT[64][68];   // [i][r]   (68: keep 16B alignment + spread banks)
    __shared__ float esT[64][68];   // [k][r]
    int t  = threadIdx.x;
    int e0 = blockIdx.x * 64;

    {   // stage: thread t loads 16 contiguous floats of one h-row and one e2-row
        int r  = t >> 2;
        int i0 = (t & 3) << 4;
        int sidx = src[e0 + r];
        const float4* hr = (const float4*)(h  + sidx * 64 + i0);
        const float4* er = (const float4*)(e2 + (size_t)(e0 + r) * 64 + i0);
#pragma unroll
        for (int q4 = 0; q4 < 4; q4++) {
            float4 hv = hr[q4];
            float4 ev = er[q4];
            int i = i0 + q4 * 4;
            hsT[i + 0][r] = hv.x; hsT[i + 1][r] = hv.y;
            hsT[i + 2][r] = hv.z; hsT[i + 3][r] = hv.w;
            esT[i + 0][r] = ev.x; esT[i + 1][r] = ev.y;
            esT[i + 2][r] = ev.z; esT[i + 3][r] = ev.w;
        }
    }
    __syncthreads();

    int r0 = (t >> 4) * 4;        // 16 row-groups of 4 edges
    int c0 = (t & 15) * 4;        // 16 col-groups of 4 outputs
    float acc[4][4] = {{0.f}};

    for (int i = 0; i < 64; i += 2) {
        float4 a0 = *(const float4*)(&hsT[i    ][r0]);
        float4 a1 = *(const float4*)(&hsT[i + 1][r0]);
        const float* bp0 = Bm + ((size_t)i << 12) + c0;          // rows i*64 + k
        const float* bp1 = bp0 + 4096;                           // rows (i+1)*64 + k
#pragma unroll 4
        for (int k = 0; k < 64; k++) {
            float4 e4 = *(const float4*)(&esT[k][r0]);
            float4 b0 = *(const float4*)(bp0 + (k << 6));
            float4 b1 = *(const float4*)(bp1 + (k << 6));
            float u00 = a0.x * e4.x, u01 = a0.y * e4.y, u02 = a0.z * e4.z, u03 = a0.w * e4.w;
            float u10 = a1.x * e4.x, u11 = a1.y * e4.y, u12 = a1.z * e4.z, u13 = a1.w * e4.w;
            acc[0][0] += u00 * b0.x; acc[0][1] += u00 * b0.y; acc[0][2] += u00 * b0.z; acc[0][3] += u00 * b0.w;
            acc[1][0] += u01 * b0.x; acc[1][1] += u01 * b0.y; acc[1][2] += u01 * b0.z; acc[1][3] += u01 * b0.w;
            acc[2][0] += u02 * b0.x; acc[2][1] += u02 * b0.y; acc[2][2] += u02 * b0.z; acc[2][3] += u02 * b0.w;
            acc[3][0] += u03 * b0.x; acc[3][1] += u03 * b0.y; acc[3][2] += u03 * b0.z; acc[3][3] += u03 * b0.w;
            acc[0][0] += u10 * b1.x; acc[0][1] += u10 * b1.y; acc[0][2] += u10 * b1.z; acc[0][3] += u10 * b1.w;
            acc[1][0] += u11 * b1.x; acc[1][1] += u11 * b1.y; acc[1][2] += u11 * b1.z; acc[1][3] += u11 * b1.w;
            acc[2][0] += u12 * b1.x; acc[2][1] += u12 * b1.y; acc[2][2] += u12 * b1.z; acc[2][3] += u12 * b1.w;
            acc[3][0] += u13 * b1.x; acc[3][1] += u13 * b1.y; acc[3][2] += u13 * b1.z; acc[3][3] += u13 * b1.w;
        }
    }

    // bias term: acc[rr][cc] += sum_i hsT[i][r0+rr] * Bm[(4096+i)*64 + c0+cc]
    {
        const float* bb = Bm + 262144 + c0;
#pragma unroll 4
        for (int i = 0; i < 64; i++) {
            float4 a4 = *(const float4*)(&hsT[i][r0]);
            float4 b4 = *(const float4*)(bb + (i << 6));
            acc[0][0] += a4.x * b4.x; acc[0][1] += a4.x * b4.y; acc[0][2] += a4.x * b4.z; acc[0][3] += a4.x * b4.w;
            acc[1][0] += a4.y * b4.x; acc[1][1] += a4.y * b4.y; acc[1][2] += a4.y * b4.z; acc[1][3] += a4.y * b4.w;
            acc[2][0] += a4.z * b4.x; acc[2][1] += a4.z * b4.y; acc[2][2] += a4.z * b4.z; acc[2][3] += a4.z * b4.w;
            acc[3][0] += a4.w * b4.x; acc[3][1] += a4.w * b4.y; acc[3][2] += a4.w * b4.z; acc[3][3] += a4.w * b4.w;
        }
    }

    int drow[4];
#pragma unroll
    for (int rr = 0; rr < 4; rr++) drow[rr] = dst[e0 + r0 + rr];
#pragma unroll
    for (int rr = 0; rr < 4; rr++)
#pragma unroll
        for (int cc = 0; cc < 4; cc++)
            atomicAdd(&agg[(size_t)drow[rr] * 64 + c0 + cc], acc[rr][cc]);
}

// ---------------------------------------------------------------- node update: root GEMM + LN + residual
__global__ __launch_bounds__(256) void k_node(const float* __restrict__ agg,
                                              const float* __restrict__ deg,
                                              const float* __restrict__ rw,
                                              const float* __restrict__ rb,
                                              const float* __restrict__ lg,
                                              const float* __restrict__ lb,
                                              float* __restrict__ h) {
    __shared__ float rws[64][65];
    __shared__ float hrow[4][64];
    int t = threadIdx.x;
    for (int idx = t; idx < 4096; idx += 256) rws[idx >> 6][idx & 63] = rw[idx];
    int g = t >> 6, j = t & 63;
    int n = blockIdx.x * 4 + g;
    float hv = h[(size_t)n * 64 + j];
    hrow[g][j] = hv;
    __syncthreads();
    float v = rb[j] + agg[(size_t)n * 64 + j] / fmaxf(deg[n], 1.0f);
#pragma unroll 8
    for (int i = 0; i < 64; i++) v += hrow[g][i] * rws[j][i];
    // LayerNorm across the 64 lanes of this wave
    float mu = v;
#pragma unroll
    for (int m = 32; m > 0; m >>= 1) mu += __shfl_xor(mu, m);
    mu *= (1.f / 64.f);
    float d = v - mu;
    float var = d * d;
#pragma unroll
    for (int m = 32; m > 0; m >>= 1) var += __shfl_xor(var, m);
    var *= (1.f / 64.f);
    float o = d * rsqrtf(var + LN_EPS) * lg[j] + lb[j];
    h[(size_t)n * 64 + j] = leaky(o) + hv;
}

// ---------------------------------------------------------------- global mean pool (run-compressed atomics)
__global__ __launch_bounds__(256) void k_pool(const float* __restrict__ h,
                                              const int* __restrict__ batch,
                                              float* __restrict__ pooled,
                                              float* __restrict__ cnt) {
    int t = threadIdx.x;
    int g = t >> 6, j = t & 63;
    int n0 = blockIdx.x * 32 + g * 8;
    int cur = batch[n0];
    float acc = 0.f, cacc = 0.f;
    for (int q = 0; q < 8; q++) {
        int n = n0 + q;
        int b = batch[n];
        float v = h[(size_t)n * 64 + j];
        if (b != cur) {
            atomicAdd(&pooled[cur * 64 + j], acc);
            if (j == 0) atomicAdd(&cnt[cur], cacc);
            acc = 0.f; cacc = 0.f; cur = b;
        }
        acc += v; cacc += 1.f;
    }
    atomicAdd(&pooled[cur * 64 + j], acc);
    if (j == 0) atomicAdd(&cnt[cur], cacc);
}

// ---------------------------------------------------------------- prediction head (1 block)
__global__ __launch_bounds__(256) void k_head(const float* __restrict__ pooled,
                                              const float* __restrict__ cnt,
                                              const float* __restrict__ pw1, const float* __restrict__ pb1,
                                              const float* __restrict__ pw2, const float* __restrict__ pb2,
                                              const float* __restrict__ pw3, const float* __restrict__ pb3,
                                              float* __restrict__ out) {
    __shared__ float ps[32][64];
    __shared__ float p1[32][64];
    __shared__ float p2[32][32];
    int t = threadIdx.x;
    for (int idx = t; idx < 2048; idx += 256) {
        int b = idx >> 6, j = idx & 63;
        ps[b][j] = pooled[idx] / fmaxf(cnt[b], 1.0f);
    }
    __syncthreads();
    for (int idx = t; idx < 2048; idx += 256) {
        int b = idx >> 6, j = idx & 63;
        float v = pb1[j];
#pragma unroll 8
        for (int i = 0; i < 64; i++) v += ps[b][i] * pw1[j * 64 + i];
        p1[b][j] = leaky(v);
    }
    __syncthreads();
    for (int idx = t; idx < 1024; idx += 256) {
        int b = idx >> 5, j = idx & 31;
        float v = pb2[j];
#pragma unroll 8
        for (int i = 0; i < 64; i++) v += p1[b][i] * pw2[j * 64 + i];
        p2[b][j] = leaky(v);
    }
    __syncthreads();
    if (t < 32) {
        float v = pb3[0];
#pragma unroll 8
        for (int i = 0; i < 32; i++) v += p2[t][i] * pw3[i];
        out[t] = v;
    }
}

// ----------------------------------------------------------------
extern "C" void kernel_launch(void* const* d_in, const int* in_sizes, int n_in,
                              void* d_out, int out_size, void* d_ws, size_t ws_size,
                              hipStream_t stream) {
    const float* x    = (const float*)d_in[0];
    const int*   eidx = (const int*)  d_in[1];
    const float* ea   = (const float*)d_in[2];
    const int*   bat  = (const int*)  d_in[3];
    const float* Win  = (const float*)d_in[4];
    const float* bin  = (const float*)d_in[5];
    const float* ew1  = (const float*)d_in[6];
    const float* eb1  = (const float*)d_in[7];
    const float* ew2  = (const float*)d_in[8];
    const float* eb2  = (const float*)d_in[9];
    const float* ew3  = (const float*)d_in[10];
    const float* eb3  = (const float*)d_in[11];
    const float* rw   = (const float*)d_in[12];
    const float* rb   = (const float*)d_in[13];
    const float* lg   = (const float*)d_in[14];
    const float* lb   = (const float*)d_in[15];
    const float* pw1  = (const float*)d_in[16];
    const float* pb1  = (const float*)d_in[17];
    const float* pw2  = (const float*)d_in[18];
    const float* pb2  = (const float*)d_in[19];
    const float* pw3  = (const float*)d_in[20];
    const float* pb3  = (const float*)d_in[21];
    float* out = (float*)d_out;

    // workspace layout (floats): ~26.3 MB total
    float* ws     = (float*)d_ws;
    float* h      = ws;                                 // N*H      = 1048576
    float* e2     = h   + (size_t)N_NODES * H;          // E*H      = 4194304
    float* Bm     = e2  + (size_t)N_EDGES * H;          // 4160*64  = 266240
    float* agg    = Bm  + 4160 * 64;                    // N*H      = 1048576
    float* deg    = agg + (size_t)N_NODES * H;          // N
    float* pooled = deg + N_NODES;                      // NB*H
    float* cnt    = pooled + NB * H;                    // NB

    const int* srcp = eidx;
    const int* dstp = eidx + N_EDGES;

    hipMemsetAsync(deg, 0, N_NODES * sizeof(float), stream);
    hipMemsetAsync(pooled, 0, (NB * H + NB) * sizeof(float), stream);

    k_deg   <<<N_EDGES / 256, 256, 0, stream>>>(dstp, deg);
    k_inproj<<<N_NODES * H / 256, 256, 0, stream>>>(x, Win, bin, h);

    for (int l = 0; l < NLAYERS; l++) {
        hipMemsetAsync(agg, 0, (size_t)N_NODES * H * sizeof(float), stream);
        k_prep_bm <<<64, 256, 0, stream>>>(ew3 + (size_t)l * 4096 * 64, eb3 + (size_t)l * 4096, Bm);
        k_edge_mlp<<<N_EDGES / 4, 256, 0, stream>>>(ea, ew1 + l * 64 * 5, eb1 + l * 64,
                                                    ew2 + l * 4096, eb2 + l * 64, e2);
        k_msg     <<<N_EDGES / 64, 256, 0, stream>>>(h, e2, Bm, srcp, dstp, agg);
        k_node    <<<N_NODES / 4, 256, 0, stream>>>(agg, deg, rw + l * 4096, rb + l * 64,
                                                    lg + l * 64, lb + l * 64, h);
    }

    k_pool<<<N_NODES / 32, 256, 0, stream>>>(h, bat, pooled, cnt);
    k_head<<<1, 256, 0, stream>>>(pooled, cnt, pw1, pb1, pw2, pb2, pw3, pb3, out);
}

// Round 3
// 479.184 us; speedup vs baseline: 3.9711x; 3.9711x over previous
//
#include <hip/hip_runtime.h>
#include <hip/hip_bf16.h>

#define N_NODES 16384
#define N_EDGES 65536
#define NB      32
#define H       64
#define NLAYERS 3
#define NEG     0.1f
#define LN_EPS  1e-5f

typedef _Float16 f16;
typedef _Float16 f16x2 __attribute__((ext_vector_type(2)));
typedef _Float16 f16x8 __attribute__((ext_vector_type(8)));
typedef __fp16   hf16x2 __attribute__((ext_vector_type(2)));
typedef float    f32x16 __attribute__((ext_vector_type(16)));

union F16x8 { f16x8 v; f16x2 p[4]; int4 i4; int2 i2[2]; };
union F16x2U { f16x2 h2; hf16x2 raw; unsigned int u; };

__device__ __forceinline__ f16x2 pkrtz(float a, float b) {
    F16x2U t; t.raw = __builtin_amdgcn_cvt_pkrtz(a, b); return t.h2;
}

__device__ __forceinline__ float leaky(float v) { return v > 0.f ? v : NEG * v; }

__device__ __forceinline__ void load_lds16(const void* g, void* l) {
    __builtin_amdgcn_global_load_lds(
        (__attribute__((address_space(1))) unsigned int*)g,
        (__attribute__((address_space(3))) unsigned int*)l, 16, 0, 0);
}

// ---------------------------------------------------------------- degree
__global__ __launch_bounds__(256) void k_deg(const int* __restrict__ dst,
                                             float* __restrict__ deg) {
    int e = blockIdx.x * 256 + threadIdx.x;
    if (e < N_EDGES) atomicAdd(&deg[dst[e]], 1.0f);
}

// ---------------------------------------------------------------- input proj
__global__ __launch_bounds__(256) void k_inproj(const float* __restrict__ x,
                                                const float* __restrict__ Win,
                                                const float* __restrict__ bin,
                                                float* __restrict__ h) {
    int t = blockIdx.x * 256 + threadIdx.x;
    int n = t >> 6, j = t & 63;
    const float* xr = x + n * 4;
    const float* wr = Win + j * 4;
    float v = bin[j] + xr[0] * wr[0] + xr[1] * wr[1] + xr[2] * wr[2] + xr[3] * wr[3];
    h[t] = leaky(v);
}

// ---------------------------------------------------------------- Bp: MFMA-fragment-ready f16 B
// frag slot = i*8 + ks*2 + oq  (i in [0,64]; i==64 is the eb3 bias slot)
// Bp[slot*512 + lane*8 + j] = B[k][o],  k = ks*16 + (lane>>5)*8 + j,  o = oq*32 + (lane&31)
// i<64: B[k][o] = ew3[(i*64 + o)*64 + k];  bias: B[k][o] = eb3[k*64 + o] (k plays i)
__global__ __launch_bounds__(256) void k_prep_bp(const float* __restrict__ ew3l,
                                                 const float* __restrict__ eb3l,
                                                 f16* __restrict__ Bp) {
    int tg   = blockIdx.x * 256 + threadIdx.x;    // 130*256 = 520 slots * 64 lanes
    int lane = tg & 63;
    int slot = tg >> 6;                           // 0..519
    int i    = slot >> 3;
    int rem  = slot & 7;
    int ks   = rem >> 1;
    int oq   = rem & 1;
    int o    = oq * 32 + (lane & 31);
    int k0   = ks * 16 + (lane >> 5) * 8;
    float v[8];
    if (i < 64) {
        const float* s = ew3l + ((size_t)(i * 64 + o)) * 64 + k0;
        float4 a = ((const float4*)s)[0];
        float4 b = ((const float4*)s)[1];
        v[0] = a.x; v[1] = a.y; v[2] = a.z; v[3] = a.w;
        v[4] = b.x; v[5] = b.y; v[6] = b.z; v[7] = b.w;
    } else {
#pragma unroll
        for (int j = 0; j < 8; j++) v[j] = eb3l[(k0 + j) * 64 + o];
    }
    union { int4 i4; f16 a[8]; } out;
#pragma unroll
    for (int j = 0; j < 8; j++) out.a[j] = (f16)v[j];   // RNE
    *(int4*)(Bp + (size_t)slot * 512 + lane * 8) = out.i4;
}

// ---------------------------------------------------------------- edge MLP stages 1+2
__global__ __launch_bounds__(256) void k_edge_mlp(const float* __restrict__ ea,
                                                  const float* __restrict__ w1,
                                                  const float* __restrict__ b1,
                                                  const float* __restrict__ w2,
                                                  const float* __restrict__ b2,
                                                  float* __restrict__ e2out) {
    __shared__ float w2s[64][65];
    __shared__ float e1s[4][64];
    int t = threadIdx.x;
    for (int idx = t; idx < 4096; idx += 256) w2s[idx >> 6][idx & 63] = w2[idx];
    int el = t >> 6, j = t & 63;
    int e = blockIdx.x * 4 + el;
    const float* ar  = ea + e * 5;
    const float* w1r = w1 + j * 5;
    float v = b1[j];
#pragma unroll
    for (int d = 0; d < 5; d++) v += ar[d] * w1r[d];
    e1s[el][j] = leaky(v);
    __syncthreads();
    float v2 = b2[j];
#pragma unroll 8
    for (int k = 0; k < 64; k++) v2 += e1s[el][k] * w2s[j][k];
    e2out[e * 64 + j] = leaky(v2);
}

// ---------------------------------------------------------------- fused bilinear MFMA GEMM + scatter
// block = 128 edges, 4 waves: wave (eq2, oq) computes edges eq2*64..+63 (2 tiles of 32) x outputs oq*32..+31
#define HS_STRIDE 76   // shorts; 152 B rows -> dword stride 38, gcd(38,32)=2 -> 2-way (free)
__global__ __launch_bounds__(256, 2) void k_msg(const float* __restrict__ h,
                                                const float* __restrict__ e2,
                                                const f16* __restrict__ Bp,
                                                const int* __restrict__ src,
                                                const int* __restrict__ dst,
                                                float* __restrict__ agg) {
    __shared__ __align__(16) f16 BufB[2][8192];                   // 2 x 16KB (16 frags each)
    __shared__ __align__(16) unsigned short hsL[128 * HS_STRIDE]; // [e][i] f16 bits
    __shared__ int dstL[128];

    const int t    = threadIdx.x;
    const int lane = t & 63;
    const int w    = t >> 6;
    const int eq2  = w >> 1, oq = w & 1;
    const int m    = lane & 31;
    const int kp   = lane >> 5;
    const int eb   = blockIdx.x * 128;

    // ---- async stage chunk 0 (frags 0..15) into BufB[0]
    {
        const f16* gsrc = Bp + (size_t)w * 2048;
#pragma unroll
        for (int q = 0; q < 4; q++)
            load_lds16(gsrc + q * 512 + lane * 8,
                       (char*)(&BufB[0][0]) + w * 4096 + q * 1024);
    }

    // ---- stage h rows (gathered by src, fp32 -> f16) into hsL; dst into dstL
    {
        int e    = t >> 1;
        int half = t & 1;
        int nsrc = src[eb + e];
        const float4* hr = (const float4*)(h + (size_t)nsrc * 64 + half * 32);
        unsigned int* hrow = (unsigned int*)hsL + e * (HS_STRIDE / 2) + half * 16;
#pragma unroll
        for (int q = 0; q < 8; q++) {
            float4 v = hr[q];
            F16x2U p0, p1;
            p0.raw = __builtin_amdgcn_cvt_pkrtz(v.x, v.y);
            p1.raw = __builtin_amdgcn_cvt_pkrtz(v.z, v.w);
            hrow[q * 2 + 0] = p0.u;
            hrow[q * 2 + 1] = p1.u;
        }
        if (t < 128) dstL[t] = dst[eb + t];
    }

    // ---- e2 rows for this lane's two A-tiles, packed f16 pairs (32 VGPRs)
    f16x2 e2p[2][4][4];
#pragma unroll
    for (int et = 0; et < 2; et++) {
        const float* row = e2 + (size_t)(eb + eq2 * 64 + et * 32 + m) * 64;
#pragma unroll
        for (int ks = 0; ks < 4; ks++) {
            int k0 = ks * 16 + kp * 8;
            float4 a = *(const float4*)(row + k0);
            float4 b = *(const float4*)(row + k0 + 4);
            e2p[et][ks][0] = pkrtz(a.x, a.y);
            e2p[et][ks][1] = pkrtz(a.z, a.w);
            e2p[et][ks][2] = pkrtz(b.x, b.y);
            e2p[et][ks][3] = pkrtz(b.z, b.w);
        }
    }
    __syncthreads();

    f32x16 C0 = {0,0,0,0,0,0,0,0,0,0,0,0,0,0,0,0};
    f32x16 C1 = {0,0,0,0,0,0,0,0,0,0,0,0,0,0,0,0};

    const unsigned short* hp0 = hsL + (eq2 * 64 + m) * HS_STRIDE;
    const unsigned short* hp1 = hp0 + 32 * HS_STRIDE;

    for (int c = 0; c <= 32; c++) {
        if (c < 32) {   // prefetch next chunk (2 i-slots = 16 frags = 16KB)
            const f16* gsrc = Bp + (size_t)(c + 1) * 8192 + w * 2048;
            char* ldst = (char*)(&BufB[(c + 1) & 1][0]) + w * 4096;
#pragma unroll
            for (int q = 0; q < 4; q++)
                load_lds16(gsrc + q * 512 + lane * 8, ldst + q * 1024);
        }
        const f16* Bc = &BufB[c & 1][0];
        if (c < 32) {
#pragma unroll
            for (int di = 0; di < 2; di++) {
                int i = c * 2 + di;
                unsigned int r0 = hp0[i];
                unsigned int r1 = hp1[i];
                F16x2U hh0, hh1;
                hh0.u = __builtin_amdgcn_perm(r0, r0, 0x01000100u);
                hh1.u = __builtin_amdgcn_perm(r1, r1, 0x01000100u);
#pragma unroll
                for (int ks = 0; ks < 4; ks++) {
                    F16x8 Bf;
                    Bf.i4 = *(const int4*)(Bc + (((di * 4 + ks) * 2 + oq) << 9) + lane * 8);
                    F16x8 A0, A1;
#pragma unroll
                    for (int r = 0; r < 4; r++) {
                        A0.p[r] = hh0.h2 * e2p[0][ks][r];
                        A1.p[r] = hh1.h2 * e2p[1][ks][r];
                    }
                    C0 = __builtin_amdgcn_mfma_f32_32x32x16_f16(A0.v, Bf.v, C0, 0, 0, 0);
                    C1 = __builtin_amdgcn_mfma_f32_32x32x16_f16(A1.v, Bf.v, C1, 0, 0, 0);
                }
            }
        } else {
            // bias slot: A = h itself (k plays the i role), B from eb3 frags
#pragma unroll
            for (int ks = 0; ks < 4; ks++) {
                F16x8 Bf;
                Bf.i4 = *(const int4*)(Bc + ((ks * 2 + oq) << 9) + lane * 8);
                int koff = (ks * 16 + kp * 8) * 2;
                const char* r0p = (const char*)hsL + (size_t)(eq2 * 64 + m) * (HS_STRIDE * 2) + koff;
                const char* r1p = r0p + 32 * (HS_STRIDE * 2);
                F16x8 A0, A1;
                A0.i2[0] = *(const int2*)(r0p);
                A0.i2[1] = *(const int2*)(r0p + 8);
                A1.i2[0] = *(const int2*)(r1p);
                A1.i2[1] = *(const int2*)(r1p + 8);
                C0 = __builtin_amdgcn_mfma_f32_32x32x16_f16(A0.v, Bf.v, C0, 0, 0, 0);
                C1 = __builtin_amdgcn_mfma_f32_32x32x16_f16(A1.v, Bf.v, C1, 0, 0, 0);
            }
        }
        __syncthreads();
    }

    // ---- scatter epilogue: C/D layout col=lane&31, row=(reg&3)+8*(reg>>2)+4*(lane>>5)
    int o = oq * 32 + (lane & 31);
#pragma unroll
    for (int reg = 0; reg < 16; reg++) {
        int r = (reg & 3) + 8 * (reg >> 2) + 4 * kp;
        atomicAdd(&agg[(size_t)dstL[eq2 * 64 + r] * 64 + o], C0[reg]);
    }
#pragma unroll
    for (int reg = 0; reg < 16; reg++) {
        int r = (reg & 3) + 8 * (reg >> 2) + 4 * kp;
        atomicAdd(&agg[(size_t)dstL[eq2 * 64 + 32 + r] * 64 + o], C1[reg]);
    }
}

// ---------------------------------------------------------------- node update: root GEMM + LN + residual
__global__ __launch_bounds__(256) void k_node(const float* __restrict__ agg,
                                              const float* __restrict__ deg,
                                              const float* __restrict__ rw,
                                              const float* __restrict__ rb,
                                              const float* __restrict__ lg,
                                              const float* __restrict__ lb,
                                              float* __restrict__ h) {
    __shared__ float rws[64][65];
    __shared__ float hrow[4][64];
    int t = threadIdx.x;
    for (int idx = t; idx < 4096; idx += 256) rws[idx >> 6][idx & 63] = rw[idx];
    int g = t >> 6, j = t & 63;
    int n = blockIdx.x * 4 + g;
    float hv = h[(size_t)n * 64 + j];
    hrow[g][j] = hv;
    __syncthreads();
    float v = rb[j] + agg[(size_t)n * 64 + j] / fmaxf(deg[n], 1.0f);
#pragma unroll 8
    for (int i = 0; i < 64; i++) v += hrow[g][i] * rws[j][i];
    float mu = v;
#pragma unroll
    for (int msk = 32; msk > 0; msk >>= 1) mu += __shfl_xor(mu, msk);
    mu *= (1.f / 64.f);
    float d = v - mu;
    float var = d * d;
#pragma unroll
    for (int msk = 32; msk > 0; msk >>= 1) var += __shfl_xor(var, msk);
    var *= (1.f / 64.f);
    float ov = d * rsqrtf(var + LN_EPS) * lg[j] + lb[j];
    h[(size_t)n * 64 + j] = leaky(ov) + hv;
}

// ---------------------------------------------------------------- global mean pool
__global__ __launch_bounds__(256) void k_pool(const float* __restrict__ h,
                                              const int* __restrict__ batch,
                                              float* __restrict__ pooled,
                                              float* __restrict__ cnt) {
    int t = threadIdx.x;
    int g = t >> 6, j = t & 63;
    int n0 = blockIdx.x * 32 + g * 8;
    int cur = batch[n0];
    float acc = 0.f, cacc = 0.f;
    for (int q = 0; q < 8; q++) {
        int n = n0 + q;
        int b = batch[n];
        float v = h[(size_t)n * 64 + j];
        if (b != cur) {
            atomicAdd(&pooled[cur * 64 + j], acc);
            if (j == 0) atomicAdd(&cnt[cur], cacc);
            acc = 0.f; cacc = 0.f; cur = b;
        }
        acc += v; cacc += 1.f;
    }
    atomicAdd(&pooled[cur * 64 + j], acc);
    if (j == 0) atomicAdd(&cnt[cur], cacc);
}

// ---------------------------------------------------------------- prediction head (1 block)
__global__ __launch_bounds__(256) void k_head(const float* __restrict__ pooled,
                                              const float* __restrict__ cnt,
                                              const float* __restrict__ pw1, const float* __restrict__ pb1,
                                              const float* __restrict__ pw2, const float* __restrict__ pb2,
                                              const float* __restrict__ pw3, const float* __restrict__ pb3,
                                              float* __restrict__ out) {
    __shared__ float ps[32][64];
    __shared__ float p1[32][64];
    __shared__ float p2[32][32];
    int t = threadIdx.x;
    for (int idx = t; idx < 2048; idx += 256) {
        int b = idx >> 6, j = idx & 63;
        ps[b][j] = pooled[idx] / fmaxf(cnt[b], 1.0f);
    }
    __syncthreads();
    for (int idx = t; idx < 2048; idx += 256) {
        int b = idx >> 6, j = idx & 63;
        float v = pb1[j];
#pragma unroll 8
        for (int i = 0; i < 64; i++) v += ps[b][i] * pw1[j * 64 + i];
        p1[b][j] = leaky(v);
    }
    __syncthreads();
    for (int idx = t; idx < 1024; idx += 256) {
        int b = idx >> 5, j = idx & 31;
        float v = pb2[j];
#pragma unroll 8
        for (int i = 0; i < 64; i++) v += p1[b][i] * pw2[j * 64 + i];
        p2[b][j] = leaky(v);
    }
    __syncthreads();
    if (t < 32) {
        float v = pb3[0];
#pragma unroll 8
        for (int i = 0; i < 32; i++) v += p2[t][i] * pw3[i];
        out[t] = v;
    }
}

// ----------------------------------------------------------------
extern "C" void kernel_launch(void* const* d_in, const int* in_sizes, int n_in,
                              void* d_out, int out_size, void* d_ws, size_t ws_size,
                              hipStream_t stream) {
    const float* x    = (const float*)d_in[0];
    const int*   eidx = (const int*)  d_in[1];
    const float* ea   = (const float*)d_in[2];
    const int*   bat  = (const int*)  d_in[3];
    const float* Win  = (const float*)d_in[4];
    const float* bin  = (const float*)d_in[5];
    const float* ew1  = (const float*)d_in[6];
    const float* eb1  = (const float*)d_in[7];
    const float* ew2  = (const float*)d_in[8];
    const float* eb2  = (const float*)d_in[9];
    const float* ew3  = (const float*)d_in[10];
    const float* eb3  = (const float*)d_in[11];
    const float* rw   = (const float*)d_in[12];
    const float* rb   = (const float*)d_in[13];
    const float* lg   = (const float*)d_in[14];
    const float* lb   = (const float*)d_in[15];
    const float* pw1  = (const float*)d_in[16];
    const float* pb1  = (const float*)d_in[17];
    const float* pw2  = (const float*)d_in[18];
    const float* pb2  = (const float*)d_in[19];
    const float* pw3  = (const float*)d_in[20];
    const float* pb3  = (const float*)d_in[21];
    float* out = (float*)d_out;

    // workspace layout (floats)
    float* ws     = (float*)d_ws;
    float* h      = ws;                                 // 1048576
    float* e2     = h   + (size_t)N_NODES * H;          // 4194304
    float* agg    = e2  + (size_t)N_EDGES * H;          // 1048576
    float* deg    = agg + (size_t)N_NODES * H;          // 16384
    float* pooled = deg + N_NODES;                      // 2048
    float* cnt    = pooled + NB * H;                    // 32
    f16*   Bp     = (f16*)(cnt + 64);                   // 528 slots * 512 f16 = 540672 B

    const int* srcp = eidx;
    const int* dstp = eidx + N_EDGES;

    (void)hipMemsetAsync(deg, 0, N_NODES * sizeof(float), stream);
    (void)hipMemsetAsync(pooled, 0, (NB * H + NB) * sizeof(float), stream);

    k_deg   <<<N_EDGES / 256, 256, 0, stream>>>(dstp, deg);
    k_inproj<<<N_NODES * H / 256, 256, 0, stream>>>(x, Win, bin, h);

    for (int l = 0; l < NLAYERS; l++) {
        (void)hipMemsetAsync(agg, 0, (size_t)N_NODES * H * sizeof(float), stream);
        k_prep_bp <<<130, 256, 0, stream>>>(ew3 + (size_t)l * 4096 * 64, eb3 + (size_t)l * 4096, Bp);
        k_edge_mlp<<<N_EDGES / 4, 256, 0, stream>>>(ea, ew1 + l * 64 * 5, eb1 + l * 64,
                                                    ew2 + l * 4096, eb2 + l * 64, e2);
        k_msg     <<<N_EDGES / 128, 256, 0, stream>>>(h, e2, Bp, srcp, dstp, agg);
        k_node    <<<N_NODES / 4, 256, 0, stream>>>(agg, deg, rw + l * 4096, rb + l * 64,
                                                    lg + l * 64, lb + l * 64, h);
    }

    k_pool<<<N_NODES / 32, 256, 0, stream>>>(h, bat, pooled, cnt);
    k_head<<<1, 256, 0, stream>>>(pooled, cnt, pw1, pb1, pw2, pb2, pw3, pb3, out);
}

// Round 4
// 369.625 us; speedup vs baseline: 5.1481x; 1.2964x over previous
//
#include <hip/hip_runtime.h>
#include <hip/hip_bf16.h>

#define N_NODES 16384
#define N_EDGES 65536
#define NB      32
#define H       64
#define NLAYERS 3
#define NEG     0.1f
#define LN_EPS  1e-5f

typedef _Float16 f16;
typedef _Float16 f16x2 __attribute__((ext_vector_type(2)));
typedef _Float16 f16x8 __attribute__((ext_vector_type(8)));
typedef __fp16   hf16x2 __attribute__((ext_vector_type(2)));
typedef float    f32x16 __attribute__((ext_vector_type(16)));

union F16x8 { f16x8 v; f16x2 p[4]; int4 i4; int2 i2[2]; };
union F16x2U { f16x2 h2; hf16x2 raw; unsigned int u; };
union F16U   { f16 h; unsigned short u; };

__device__ __forceinline__ f16x2 pkrtz(float a, float b) {
    F16x2U t; t.raw = __builtin_amdgcn_cvt_pkrtz(a, b); return t.h2;
}
__device__ __forceinline__ float leaky(float v) { return v > 0.f ? v : NEG * v; }

// ---------------------------------------------------------------- init: inproj + degree (fused)
__global__ __launch_bounds__(256) void k_init(const float* __restrict__ x,
                                              const float* __restrict__ Win,
                                              const float* __restrict__ bin,
                                              const int* __restrict__ dst,
                                              float* __restrict__ h,
                                              float* __restrict__ deg) {
    int bid = blockIdx.x;
    if (bid < 4096) {
        int t = bid * 256 + threadIdx.x;
        int n = t >> 6, j = t & 63;
        const float* xr = x + n * 4;
        const float* wr = Win + j * 4;
        float v = bin[j] + xr[0] * wr[0] + xr[1] * wr[1] + xr[2] * wr[2] + xr[3] * wr[3];
        h[t] = leaky(v);
    } else {
        int e = (bid - 4096) * 256 + threadIdx.x;
        atomicAdd(&deg[dst[e]], 1.0f);
    }
}

// ---------------------------------------------------------------- Bp (3 layers): MFMA-fragment f16 B
// slot = i*8 + ks*2 + oq (i in [0,64]; i==64 = eb3 bias). layer stride 520 slots.
// Bp[l][slot*512 + lane*8 + j] = B[k][o], k = ks*16 + (lane>>5)*8 + j, o = oq*32 + (lane&31)
__global__ __launch_bounds__(256) void k_prep_bp(const float* __restrict__ ew3,
                                                 const float* __restrict__ eb3,
                                                 f16* __restrict__ Bp) {
    int tg    = blockIdx.x * 256 + threadIdx.x;   // 390*256 = 1560 gslots * 64 lanes
    int lane  = tg & 63;
    int gslot = tg >> 6;                          // 0..1559
    int l     = gslot / 520;
    int slot  = gslot - l * 520;
    const float* ew3l = ew3 + (size_t)l * 262144;
    const float* eb3l = eb3 + (size_t)l * 4096;
    int i   = slot >> 3;
    int rem = slot & 7;
    int ks  = rem >> 1;
    int oq  = rem & 1;
    int o   = oq * 32 + (lane & 31);
    int k0  = ks * 16 + (lane >> 5) * 8;
    float v[8];
    if (i < 64) {
        const float* s = ew3l + ((size_t)(i * 64 + o)) * 64 + k0;
        float4 a = ((const float4*)s)[0];
        float4 b = ((const float4*)s)[1];
        v[0] = a.x; v[1] = a.y; v[2] = a.z; v[3] = a.w;
        v[4] = b.x; v[5] = b.y; v[6] = b.z; v[7] = b.w;
    } else {
#pragma unroll
        for (int j = 0; j < 8; j++) v[j] = eb3l[(k0 + j) * 64 + o];
    }
    union { int4 i4; f16 a[8]; } out;
#pragma unroll
    for (int j = 0; j < 8; j++) out.a[j] = (f16)v[j];
    *(int4*)(Bp + (size_t)l * 266240 + (size_t)slot * 512 + lane * 8) = out.i4;
}

// ---------------------------------------------------------------- edge MLP (MFMA stage2), f16 output
// block = 128 edges, 4 waves (eq2, oq) like k_msg. e2h: u16[E][64] (f16 bits, k-contiguous).
__global__ __launch_bounds__(256) void k_edge_mlp(const float* __restrict__ ea,
                                                  const float* __restrict__ w1,
                                                  const float* __restrict__ b1,
                                                  const float* __restrict__ w2,
                                                  const float* __restrict__ b2,
                                                  unsigned short* __restrict__ e2h) {
    __shared__ float eas[128 * 8];                      // padded edge_attr rows (5 -> 8)
    __shared__ __align__(16) unsigned short e1L[128 * 72]; // [e][kk] f16, 144B rows (16B aligned)
    int t = threadIdx.x;
    int eb = blockIdx.x * 128;

    for (int idx = t; idx < 640; idx += 256) {
        int r = idx / 5, d = idx - r * 5;
        eas[r * 8 + d] = ea[(size_t)eb * 5 + idx];
    }
    __syncthreads();

    // ---- phase 1: e1 = leaky(ea @ w1^T + b1), f16 into e1L
    {
        int kk = t & 63;
        int eg = t >> 6;
        float w1r[5];
#pragma unroll
        for (int d = 0; d < 5; d++) w1r[d] = w1[kk * 5 + d];
        float b1r = b1[kk];
        for (int g = 0; g < 32; g++) {
            int row = g * 4 + eg;
            float4 a4 = *(const float4*)(eas + row * 8);
            float a5 = eas[row * 8 + 4];
            float v = b1r + a4.x * w1r[0] + a4.y * w1r[1] + a4.z * w1r[2] + a4.w * w1r[3] + a5 * w1r[4];
            F16U z; z.h = (f16)leaky(v);
            e1L[row * 72 + kk] = z.u;
        }
    }
    __syncthreads();

    // ---- phase 2: e2 = leaky(e1 @ w2^T + b2) via MFMA; wave (eq2, oq)
    int lane = t & 63;
    int w    = t >> 6;
    int eq2  = w >> 1, oq = w & 1;
    int m    = lane & 31;
    int kp   = lane >> 5;

    F16x8 Bf[4];
#pragma unroll
    for (int ks = 0; ks < 4; ks++) {
        const float* s = w2 + (size_t)(oq * 32 + m) * 64 + ks * 16 + kp * 8;
        float4 a = ((const float4*)s)[0];
        float4 b = ((const float4*)s)[1];
        Bf[ks].p[0] = pkrtz(a.x, a.y);
        Bf[ks].p[1] = pkrtz(a.z, a.w);
        Bf[ks].p[2] = pkrtz(b.x, b.y);
        Bf[ks].p[3] = pkrtz(b.z, b.w);
    }
    float b2r = b2[oq * 32 + m];

    f32x16 C0 = {0,0,0,0,0,0,0,0,0,0,0,0,0,0,0,0};
    f32x16 C1 = {0,0,0,0,0,0,0,0,0,0,0,0,0,0,0,0};
#pragma unroll
    for (int ks = 0; ks < 4; ks++) {
        int koff = (ks * 16 + kp * 8);
        F16x8 A0, A1;
        A0.i4 = *(const int4*)(e1L + (size_t)(eq2 * 64 + m) * 72 + koff);
        A1.i4 = *(const int4*)(e1L + (size_t)(eq2 * 64 + 32 + m) * 72 + koff);
        C0 = __builtin_amdgcn_mfma_f32_32x32x16_f16(A0.v, Bf[ks].v, C0, 0, 0, 0);
        C1 = __builtin_amdgcn_mfma_f32_32x32x16_f16(A1.v, Bf[ks].v, C1, 0, 0, 0);
    }

    // epilogue: C layout col=lane&31 (=o), row=(reg&3)+8*(reg>>2)+4*kp (=edge within tile)
    int o = oq * 32 + m;
#pragma unroll
    for (int reg = 0; reg < 16; reg++) {
        int r = (reg & 3) + 8 * (reg >> 2) + 4 * kp;
        F16U z; z.h = (f16)leaky(C0[reg] + b2r);
        e2h[(size_t)(eb + eq2 * 64 + r) * 64 + o] = z.u;
    }
#pragma unroll
    for (int reg = 0; reg < 16; reg++) {
        int r = (reg & 3) + 8 * (reg >> 2) + 4 * kp;
        F16U z; z.h = (f16)leaky(C1[reg] + b2r);
        e2h[(size_t)(eb + eq2 * 64 + 32 + r) * 64 + o] = z.u;
    }
}

// ---------------------------------------------------------------- fused bilinear MFMA GEMM + scatter
#define HS_STRIDE 76   // u16; 152 B rows (8B aligned, 2-way LDS banks = free)

__device__ __forceinline__ void loadB8(const f16* __restrict__ Bp, int c, int oq, int lane, F16x8* dstB) {
    const f16* base = Bp + (((size_t)(c * 16 + oq)) << 9) + lane * 8;
#pragma unroll
    for (int di = 0; di < 2; di++)
#pragma unroll
        for (int ks = 0; ks < 4; ks++)
            dstB[di * 4 + ks].i4 = *(const int4*)(base + ((di * 8 + ks * 2) << 9));
}
__device__ __forceinline__ void loadB4(const f16* __restrict__ Bp, int oq, int lane, F16x8* dstB) {
    const f16* base = Bp + (((size_t)(512 + oq)) << 9) + lane * 8;
#pragma unroll
    for (int ks = 0; ks < 4; ks++)
        dstB[ks].i4 = *(const int4*)(base + ((ks * 2) << 9));
}

__device__ __forceinline__ void msg_chunk(int c, const F16x8* Bc,
                                          const unsigned short* hp0, const unsigned short* hp1,
                                          const f16x2 (*e2p)[4][4], f32x16& C0, f32x16& C1) {
    unsigned int rr0 = *(const unsigned int*)(hp0 + 2 * c);   // h[2c] | h[2c+1]
    unsigned int rr1 = *(const unsigned int*)(hp1 + 2 * c);
#pragma unroll
    for (int di = 0; di < 2; di++) {
        F16x2U hh0, hh1;
        unsigned int sel = di ? 0x03020302u : 0x01000100u;
        hh0.u = __builtin_amdgcn_perm(rr0, rr0, sel);
        hh1.u = __builtin_amdgcn_perm(rr1, rr1, sel);
#pragma unroll
        for (int ks = 0; ks < 4; ks++) {
            F16x8 A0, A1;
#pragma unroll
            for (int r = 0; r < 4; r++) {
                A0.p[r] = hh0.h2 * e2p[0][ks][r];
                A1.p[r] = hh1.h2 * e2p[1][ks][r];
            }
            C0 = __builtin_amdgcn_mfma_f32_32x32x16_f16(A0.v, Bc[di * 4 + ks].v, C0, 0, 0, 0);
            C1 = __builtin_amdgcn_mfma_f32_32x32x16_f16(A1.v, Bc[di * 4 + ks].v, C1, 0, 0, 0);
        }
    }
}

__global__ __launch_bounds__(256, 2) void k_msg(const float* __restrict__ h,
                                                const unsigned int* __restrict__ e2h,
                                                const f16* __restrict__ Bp,
                                                const int* __restrict__ src,
                                                const int* __restrict__ dst,
                                                float* __restrict__ agg) {
    __shared__ __align__(16) unsigned short hsL[128 * HS_STRIDE];
    __shared__ int dstL[128];

    const int t    = threadIdx.x;
    const int lane = t & 63;
    const int w    = t >> 6;
    const int eq2  = w >> 1, oq = w & 1;
    const int m    = lane & 31;
    const int kp   = lane >> 5;
    const int eb   = blockIdx.x * 128;

    // ---- stage h rows (gathered by src, fp32 -> f16) into hsL; dst into dstL
    {
        int e    = t >> 1;
        int half = t & 1;
        int nsrc = src[eb + e];
        const float4* hr = (const float4*)(h + (size_t)nsrc * 64 + half * 32);
        unsigned int* hrow = (unsigned int*)hsL + e * (HS_STRIDE / 2) + half * 16;
#pragma unroll
        for (int q = 0; q < 8; q++) {
            float4 v = hr[q];
            F16x2U p0, p1;
            p0.raw = __builtin_amdgcn_cvt_pkrtz(v.x, v.y);
            p1.raw = __builtin_amdgcn_cvt_pkrtz(v.z, v.w);
            hrow[q * 2 + 0] = p0.u;
            hrow[q * 2 + 1] = p1.u;
        }
        if (t < 128) dstL[t] = dst[eb + t];
    }

    // ---- e2 rows (already f16 pairs) for this lane's two A-tiles
    f16x2 e2p[2][4][4];
#pragma unroll
    for (int et = 0; et < 2; et++) {
        const unsigned int* row = e2h + (size_t)(eb + eq2 * 64 + et * 32 + m) * 32;
#pragma unroll
        for (int ks = 0; ks < 4; ks++) {
            int4 q = *(const int4*)(row + ks * 8 + kp * 4);
            F16x2U u0, u1, u2, u3;
            u0.u = q.x; u1.u = q.y; u2.u = q.z; u3.u = q.w;
            e2p[et][ks][0] = u0.h2; e2p[et][ks][1] = u1.h2;
            e2p[et][ks][2] = u2.h2; e2p[et][ks][3] = u3.h2;
        }
    }
    __syncthreads();

    f32x16 C0 = {0,0,0,0,0,0,0,0,0,0,0,0,0,0,0,0};
    f32x16 C1 = {0,0,0,0,0,0,0,0,0,0,0,0,0,0,0,0};

    const unsigned short* hp0 = hsL + (eq2 * 64 + m) * HS_STRIDE;
    const unsigned short* hp1 = hp0 + 32 * HS_STRIDE;

    // ---- barrier-free K-loop: 3-buffer register pipeline, depth 2
    F16x8 B0[8], B1[8], B2[8];
    loadB8(Bp, 0, oq, lane, B0);
    loadB8(Bp, 1, oq, lane, B1);
    int c = 0;
    for (int it = 0; it < 10; it++) {
        loadB8(Bp, c + 2, oq, lane, B2); msg_chunk(c, B0, hp0, hp1, e2p, C0, C1); c++;
        loadB8(Bp, c + 2, oq, lane, B0); msg_chunk(c, B1, hp0, hp1, e2p, C0, C1); c++;
        loadB8(Bp, c + 2, oq, lane, B1); msg_chunk(c, B2, hp0, hp1, e2p, C0, C1); c++;
    }
    // c == 30: B0 holds 30, B1 holds 31
    loadB4(Bp, oq, lane, B2);                       // bias frags
    msg_chunk(30, B0, hp0, hp1, e2p, C0, C1);
    msg_chunk(31, B1, hp0, hp1, e2p, C0, C1);
    // bias chunk: A = h itself (k plays the i role)
#pragma unroll
    for (int ks = 0; ks < 4; ks++) {
        int koff = (ks * 16 + kp * 8) * 2;
        const char* r0p = (const char*)hsL + (size_t)(eq2 * 64 + m) * (HS_STRIDE * 2) + koff;
        const char* r1p = r0p + 32 * (HS_STRIDE * 2);
        F16x8 A0, A1;
        A0.i2[0] = *(const int2*)(r0p); A0.i2[1] = *(const int2*)(r0p + 8);
        A1.i2[0] = *(const int2*)(r1p); A1.i2[1] = *(const int2*)(r1p + 8);
        C0 = __builtin_amdgcn_mfma_f32_32x32x16_f16(A0.v, B2[ks].v, C0, 0, 0, 0);
        C1 = __builtin_amdgcn_mfma_f32_32x32x16_f16(A1.v, B2[ks].v, C1, 0, 0, 0);
    }

    // ---- scatter epilogue
    int o = oq * 32 + m;
#pragma unroll
    for (int reg = 0; reg < 16; reg++) {
        int r = (reg & 3) + 8 * (reg >> 2) + 4 * kp;
        atomicAdd(&agg[(size_t)dstL[eq2 * 64 + r] * 64 + o], C0[reg]);
    }
#pragma unroll
    for (int reg = 0; reg < 16; reg++) {
        int r = (reg & 3) + 8 * (reg >> 2) + 4 * kp;
        atomicAdd(&agg[(size_t)dstL[eq2 * 64 + 32 + r] * 64 + o], C1[reg]);
    }
}

// ---------------------------------------------------------------- node update: root GEMM + LN + residual
__global__ __launch_bounds__(256) void k_node(const float* __restrict__ agg,
                                              const float* __restrict__ deg,
                                              const float* __restrict__ rw,
                                              const float* __restrict__ rb,
                                              const float* __restrict__ lg,
                                              const float* __restrict__ lb,
                                              float* __restrict__ h) {
    __shared__ float rws[64][65];
    __shared__ float hrow[4][64];
    int t = threadIdx.x;
    for (int idx = t; idx < 4096; idx += 256) rws[idx >> 6][idx & 63] = rw[idx];
    int g = t >> 6, j = t & 63;
    int n = blockIdx.x * 4 + g;
    float hv = h[(size_t)n * 64 + j];
    hrow[g][j] = hv;
    __syncthreads();
    float v = rb[j] + agg[(size_t)n * 64 + j] / fmaxf(deg[n], 1.0f);
#pragma unroll 8
    for (int i = 0; i < 64; i++) v += hrow[g][i] * rws[j][i];
    float mu = v;
#pragma unroll
    for (int msk = 32; msk > 0; msk >>= 1) mu += __shfl_xor(mu, msk);
    mu *= (1.f / 64.f);
    float d = v - mu;
    float var = d * d;
#pragma unroll
    for (int msk = 32; msk > 0; msk >>= 1) var += __shfl_xor(var, msk);
    var *= (1.f / 64.f);
    float ov = d * rsqrtf(var + LN_EPS) * lg[j] + lb[j];
    h[(size_t)n * 64 + j] = leaky(ov) + hv;
}

// ---------------------------------------------------------------- global mean pool
__global__ __launch_bounds__(256) void k_pool(const float* __restrict__ h,
                                              const int* __restrict__ batch,
                                              float* __restrict__ pooled,
                                              float* __restrict__ cnt) {
    int t = threadIdx.x;
    int g = t >> 6, j = t & 63;
    int n0 = blockIdx.x * 32 + g * 8;
    int cur = batch[n0];
    float acc = 0.f, cacc = 0.f;
    for (int q = 0; q < 8; q++) {
        int n = n0 + q;
        int b = batch[n];
        float v = h[(size_t)n * 64 + j];
        if (b != cur) {
            atomicAdd(&pooled[cur * 64 + j], acc);
            if (j == 0) atomicAdd(&cnt[cur], cacc);
            acc = 0.f; cacc = 0.f; cur = b;
        }
        acc += v; cacc += 1.f;
    }
    atomicAdd(&pooled[cur * 64 + j], acc);
    if (j == 0) atomicAdd(&cnt[cur], cacc);
}

// ---------------------------------------------------------------- prediction head (1 block)
__global__ __launch_bounds__(256) void k_head(const float* __restrict__ pooled,
                                              const float* __restrict__ cnt,
                                              const float* __restrict__ pw1, const float* __restrict__ pb1,
                                              const float* __restrict__ pw2, const float* __restrict__ pb2,
                                              const float* __restrict__ pw3, const float* __restrict__ pb3,
                                              float* __restrict__ out) {
    __shared__ float ps[32][64];
    __shared__ float p1[32][64];
    __shared__ float p2[32][32];
    int t = threadIdx.x;
    for (int idx = t; idx < 2048; idx += 256) {
        int b = idx >> 6, j = idx & 63;
        ps[b][j] = pooled[idx] / fmaxf(cnt[b], 1.0f);
    }
    __syncthreads();
    for (int idx = t; idx < 2048; idx += 256) {
        int b = idx >> 6, j = idx & 63;
        float v = pb1[j];
#pragma unroll 8
        for (int i = 0; i < 64; i++) v += ps[b][i] * pw1[j * 64 + i];
        p1[b][j] = leaky(v);
    }
    __syncthreads();
    for (int idx = t; idx < 1024; idx += 256) {
        int b = idx >> 5, j = idx & 31;
        float v = pb2[j];
#pragma unroll 8
        for (int i = 0; i < 64; i++) v += p1[b][i] * pw2[j * 64 + i];
        p2[b][j] = leaky(v);
    }
    __syncthreads();
    if (t < 32) {
        float v = pb3[0];
#pragma unroll 8
        for (int i = 0; i < 32; i++) v += p2[t][i] * pw3[i];
        out[t] = v;
    }
}

// ----------------------------------------------------------------
extern "C" void kernel_launch(void* const* d_in, const int* in_sizes, int n_in,
                              void* d_out, int out_size, void* d_ws, size_t ws_size,
                              hipStream_t stream) {
    const float* x    = (const float*)d_in[0];
    const int*   eidx = (const int*)  d_in[1];
    const float* ea   = (const float*)d_in[2];
    const int*   bat  = (const int*)  d_in[3];
    const float* Win  = (const float*)d_in[4];
    const float* bin  = (const float*)d_in[5];
    const float* ew1  = (const float*)d_in[6];
    const float* eb1  = (const float*)d_in[7];
    const float* ew2  = (const float*)d_in[8];
    const float* eb2  = (const float*)d_in[9];
    const float* ew3  = (const float*)d_in[10];
    const float* eb3  = (const float*)d_in[11];
    const float* rw   = (const float*)d_in[12];
    const float* rb   = (const float*)d_in[13];
    const float* lg   = (const float*)d_in[14];
    const float* lb   = (const float*)d_in[15];
    const float* pw1  = (const float*)d_in[16];
    const float* pb1  = (const float*)d_in[17];
    const float* pw2  = (const float*)d_in[18];
    const float* pb2  = (const float*)d_in[19];
    const float* pw3  = (const float*)d_in[20];
    const float* pb3  = (const float*)d_in[21];
    float* out = (float*)d_out;

    // workspace layout (float indices); total ~25.6 MB
    float* ws     = (float*)d_ws;
    float* h      = ws;                          // 1048576
    float* agg    = ws + 1048576;                // 3 * 1048576
    float* deg    = ws + 4194304;                // 16384
    float* pooled = ws + 4210688;                // 2048
    float* cnt    = ws + 4212736;                // 32 (+32 pad)
    unsigned int* e2h = (unsigned int*)(ws + 4212800);   // 2097152 u32 (f16[E][64])
    f16* Bp       = (f16*)(ws + 4212800 + 2097152);      // 3 * 266240 f16

    const int* srcp = eidx;
    const int* dstp = eidx + N_EDGES;

    // one memset covers agg[3] + deg + pooled + cnt (contiguous)
    (void)hipMemsetAsync(agg, 0, (size_t)(3164224) * sizeof(float), stream);

    k_init   <<<4352, 256, 0, stream>>>(x, Win, bin, dstp, h, deg);
    k_prep_bp<<<390, 256, 0, stream>>>(ew3, eb3, Bp);

    for (int l = 0; l < NLAYERS; l++) {
        float* agg_l = agg + (size_t)l * N_NODES * H;
        k_edge_mlp<<<N_EDGES / 128, 256, 0, stream>>>(ea, ew1 + l * 320, eb1 + l * 64,
                                                      ew2 + l * 4096, eb2 + l * 64,
                                                      (unsigned short*)e2h);
        k_msg     <<<N_EDGES / 128, 256, 0, stream>>>(h, e2h, Bp + (size_t)l * 266240,
                                                      srcp, dstp, agg_l);
        k_node    <<<N_NODES / 4, 256, 0, stream>>>(agg_l, deg, rw + l * 4096, rb + l * 64,
                                                    lg + l * 64, lb + l * 64, h);
    }

    k_pool<<<N_NODES / 32, 256, 0, stream>>>(h, bat, pooled, cnt);
    k_head<<<1, 256, 0, stream>>>(pooled, cnt, pw1, pb1, pw2, pb2, pw3, pb3, out);
}